// Round 1
// baseline (142.373 us; speedup 1.0000x reference)
//
#include <hip/hip_runtime.h>
#include <math.h>
#include <stdint.h>

#define B_    8
#define N_    3136
#define DIM_  147
#define KP_   160
#define TOK_  (B_*N_)      // 25088
#define QKV3_ 192
#define NSPLIT 4

typedef __attribute__((ext_vector_type(4)))  float f32x4;
typedef __attribute__((ext_vector_type(16))) float f32x16;
typedef __attribute__((ext_vector_type(4)))  unsigned int u32x4;
typedef __attribute__((ext_vector_type(8)))  short short8;
typedef union { short8 s; u32x4 u; } pk8;

static __device__ __forceinline__ unsigned short f2b(float f){
  unsigned int u = __float_as_uint(f);
  u += 0x7fffu + ((u>>16)&1u);          // RNE
  return (unsigned short)(u>>16);
}
static __device__ __forceinline__ unsigned int pk2(float a, float b){   // RNE pack
  return ((unsigned int)f2b(b)<<16) | (unsigned int)f2b(a);
}
static __device__ __forceinline__ unsigned int pk2t(float a, float b){  // trunc pack (P only)
  return (__float_as_uint(b) & 0xffff0000u) | (__float_as_uint(a)>>16);
}
static __device__ __forceinline__ float b2f(unsigned short s){
  return __uint_as_float(((unsigned int)s)<<16);
}

// async global->LDS, 16 B per lane; LDS dest = uniform base + lane*16
#define GLD16(gp, lp) __builtin_amdgcn_global_load_lds( \
    reinterpret_cast<const uint32_t __attribute__((address_space(1)))*>(reinterpret_cast<uintptr_t>(gp)), \
    reinterpret_cast<uint32_t __attribute__((address_space(3)))*>(reinterpret_cast<uintptr_t>(lp)), \
    16, 0, 0)

// ---------------------------------------------------------------- K0: pack weights -> bf16
__global__ __launch_bounds__(256) void k_prep(const float* __restrict__ qkvw,
                                              const float* __restrict__ projw,
                                              const float* __restrict__ fc1w,
                                              const float* __restrict__ fc2w,
                                              unsigned short* __restrict__ wp,
                                              unsigned short* __restrict__ wpj,
                                              unsigned short* __restrict__ w1b,
                                              unsigned short* __restrict__ w2b){
  int idx = blockIdx.x*256 + threadIdx.x;
  if(idx < QKV3_*KP_){
    int n = idx / KP_, k = idx - n*KP_;
    wp[idx] = f2b((k < DIM_) ? qkvw[n*DIM_ + k] : 0.f);
  }
  if(idx < 4096){
    wpj[idx] = f2b(projw[idx]);
    w1b[idx] = f2b(fc1w[idx]);
    w2b[idx] = f2b(fc2w[idx]);
  }
}

// ---------------------------------------------------------------- K1: fused LN1 + QKV GEMM (R9-verified)
__global__ __launch_bounds__(256) void k_qkv(const float* __restrict__ x,
                                             const float* __restrict__ w1,
                                             const float* __restrict__ b1,
                                             const unsigned short* __restrict__ wp,
                                             const float* __restrict__ scale,
                                             unsigned short* __restrict__ qb,
                                             unsigned short* __restrict__ kb,
                                             unsigned short* __restrict__ vtb,
                                             unsigned short* __restrict__ vfb){
  __shared__ alignas(16) unsigned short Wb[192*168];  // 64512 B; aliased by A_ and VT
  unsigned short* A_ = Wb;
  unsigned short* VT = Wb;
  int tid = threadIdx.x;
  int w = tid>>6, lane = tid&63, quad = lane>>4, l16 = lane&15;
  int t0 = blockIdx.x*64;
  float sc2 = scale[0] * 1.44269504089f;

  #pragma unroll
  for(int half=0; half<2; half++){
    int g = half*32 + (tid>>3), e = tid&7;
    const float* xr = x + (size_t)(t0+g)*147;
    float xv[19];
    float s = 0.f, sq = 0.f;
    #pragma unroll
    for(int i=0;i<19;i++){
      int col = e + 8*i;
      float v = (col < 147) ? xr[col] : 0.f;
      xv[i] = v; s += v; sq += v*v;
    }
    s  += __shfl_xor(s,1,64);  s  += __shfl_xor(s,2,64);  s  += __shfl_xor(s,4,64);
    sq += __shfl_xor(sq,1,64); sq += __shfl_xor(sq,2,64); sq += __shfl_xor(sq,4,64);
    float mean = s*(1.f/147.f);
    float var  = sq*(1.f/147.f) - mean*mean;
    float rstd = rsqrtf(var + 1e-5f);
    #pragma unroll
    for(int i=0;i<19;i++){
      int col = e + 8*i;
      if(col < 147) A_[g*168 + col] = f2b((xv[i]-mean)*rstd*w1[col] + b1[col]);
    }
    #pragma unroll
    for(int i=0;i<2;i++){
      int col = 144 + e + 8*i;
      if(col >= 147 && col < 160) A_[g*168 + col] = 0;
    }
  }
  __syncthreads();
  short8 Af[5];
  #pragma unroll
  for(int kk=0;kk<5;kk++)
    Af[kk] = *(const short8*)(A_ + (w*16+l16)*168 + kk*32 + quad*8);
  __syncthreads();
  {
    const u32x4* src = (const u32x4*)wp;
    unsigned int* dst = (unsigned int*)Wb;
    #pragma unroll
    for(int rep=0; rep<15; rep++){
      int idx = rep*256 + tid;
      int row = idx/20, c = idx - row*20;
      *(u32x4*)(dst + row*84 + c*4) = src[idx];
    }
  }
  __syncthreads();
  f32x4 acc[12];
  #pragma unroll
  for(int i=0;i<12;i++) acc[i] = (f32x4){0.f,0.f,0.f,0.f};
  #pragma unroll
  for(int nt=0;nt<12;nt++){
    #pragma unroll
    for(int kk=0;kk<5;kk++){
      short8 Bf = *(const short8*)(Wb + (nt*16+l16)*168 + kk*32 + quad*8);
      acc[nt] = __builtin_amdgcn_mfma_f32_16x16x32_bf16(Af[kk], Bf, acc[nt], 0,0,0);
    }
  }
  #pragma unroll
  for(int nt=0;nt<12;nt++){
    int o = nt*16 + l16;
    #pragma unroll
    for(int r=0;r<4;r++){
      int tl = w*16 + quad*4 + r;
      int mg = t0 + tl;
      float val = acc[nt][r];
      if(o < 64)        qb[(size_t)mg*64 + o]        = f2b(val*sc2);
      else if(o < 128)  kb[(size_t)mg*64 + (o-64)]   = f2b(val);
      else              vfb[(size_t)mg*64 + (o-128)] = f2b(val);
    }
  }
  __syncthreads();
  #pragma unroll
  for(int nt=8;nt<12;nt++){
    int hd = (nt-8)*16 + l16;
    #pragma unroll
    for(int r=0;r<4;r++)
      VT[hd*72 + (w*16 + quad*4 + r)] = f2b(acc[nt][r]);
  }
  __syncthreads();
  {
    int b = t0 / N_, n0 = t0 - b*N_;
    const unsigned int* VT32 = (const unsigned int*)VT;
    unsigned int* vg = (unsigned int*)vtb + ((size_t)b*64)*(N_/2) + (n0>>1);
    #pragma unroll
    for(int rep=0;rep<8;rep++){
      int f = rep*256 + tid;
      int row = f>>5, c = f&31;
      vg[(size_t)row*(N_/2) + c] = VT32[row*36 + c];
    }
  }
}

// ---------------------------------------------------------------- K2: attention — 64q block, 2 waves, KV-row split
// R10: double-buffered KV staging with counted vmcnt (T3/T4 2-phase minimum recipe).
// Old loop paid full L2/HBM latency per tile (stage -> __syncthreads drain -> compute).
// New loop: issue stage(t+1) into buf^1, then s_waitcnt vmcnt(8) (tile-t loads only) +
// raw s_barrier, compute tile t from buf, barrier (WAR for buf^1's overwrite next iter).
// Prefetch stays in flight across the barrier; never drains to 0 in the main loop.
__global__ __launch_bounds__(128,2) void k_attn(const unsigned short* __restrict__ qb,
                                                const unsigned short* __restrict__ kb,
                                                const unsigned short* __restrict__ vtb,
                                                unsigned short* __restrict__ Opart,
                                                float* __restrict__ lpart){
  __shared__ alignas(16) unsigned int L[8192];   // 2 x (K 8KB | V 8KB) double-buffered; reused for merge
  __shared__ float Lr[128];
  int tid = threadIdx.x;
  int w = tid>>6, lane = tid&63;
  int h = lane>>5, l32 = lane&31, l7 = l32&7;
  int qt = blockIdx.x, sp = blockIdx.y, b = blockIdx.z;
  int q0 = qt*64;
  int kv0 = (sp*49)>>2, kv1 = ((sp+1)*49)>>2;
  int nt = kv1 - kv0;

  // Q B-frags (32x32x16): n=l32 -> q=q0+32qh+l32; k=8h+i -> hd=16kc+8h+i
  short8 Qf[2][4];
  {
    const unsigned short* qg = qb + ((size_t)b*N_ + q0)*64;
    #pragma unroll
    for(int qh=0;qh<2;qh++)
      #pragma unroll
      for(int kc=0;kc<4;kc++)
        Qf[qh][kc] = *(const short8*)(qg + (32*qh + l32)*64 + 16*kc + 8*h);
  }
  // staging offsets: wave w covers local positions p=0..31 (global rows 32w+*)
  int koffG[4], voffG[4];
  {
    int pl = lane>>3, cl = lane&7;
    #pragma unroll
    for(int rr=0;rr<4;rr++){
      int p = rr*8 + pl;
      int sig = (p & 0x13) | ((p&4)<<1) | ((p&8)>>1);   // swap bits 2<->3
      int cx = cl ^ (p&7);                               // XOR col swizzle
      koffG[rr] = (32*w + sig)*128 + cx*16;              // K: sigma'd row, byte col
      voffG[rr] = (32*w + p)*(N_*2) + cx*16;             // V^T: plain hd row
    }
  }
  const char* kBase = (const char*)kb + (size_t)b*N_*128;
  const char* vBase = (const char*)vtb + (size_t)b*64*(size_t)(N_*2);

  f32x16 O[2][2];
  #pragma unroll
  for(int qh=0;qh<2;qh++) for(int hdq=0;hdq<2;hdq++)
    #pragma unroll
    for(int r=0;r<16;r++) O[qh][hdq][r] = 0.f;
  // split the serial lr += chain into 4 accumulators per qh (latency chain 32 -> 4x8)
  float lracc[2][4];
  #pragma unroll
  for(int qh=0;qh<2;qh++)
    #pragma unroll
    for(int j=0;j<4;j++) lracc[qh][j] = 0.f;

  // prologue: stage tile kv0 into buffer 0
  {
    const char* kT = kBase + (size_t)kv0*8192;
    const char* vT = vBase + (size_t)kv0*128;
    #pragma unroll
    for(int rr=0;rr<4;rr++) GLD16(kT + koffG[rr], (char*)L + w*4096 + rr*1024);
    #pragma unroll
    for(int rr=0;rr<4;rr++) GLD16(vT + voffG[rr], (char*)L + 8192 + w*4096 + rr*1024);
  }

  int cur = 0;
  for(int i=0;i<nt;i++){
    int kvt = kv0 + i;
    // issue next-tile stage into the other buffer (fire-and-forget), then wait only
    // for the CURRENT tile's 8 loads (8 newer stay in flight across the barrier).
    if(i+1 < nt){
      const char* kT = kBase + (size_t)(kvt+1)*8192;
      const char* vT = vBase + (size_t)(kvt+1)*128;
      char* dst = (char*)L + (cur^1)*16384;
      #pragma unroll
      for(int rr=0;rr<4;rr++) GLD16(kT + koffG[rr], dst + w*4096 + rr*1024);
      #pragma unroll
      for(int rr=0;rr<4;rr++) GLD16(vT + voffG[rr], dst + 8192 + w*4096 + rr*1024);
      asm volatile("s_waitcnt vmcnt(8)" ::: "memory");
    } else {
      asm volatile("s_waitcnt vmcnt(0)" ::: "memory");
    }
    __builtin_amdgcn_s_barrier();            // both waves' tile-i LDS writes visible
    __builtin_amdgcn_sched_barrier(0);       // pin: no ds_read hoisted above barrier

    const unsigned short* Kh = (const unsigned short*)L + cur*8192 + w*2048;
    const unsigned short* Vh = (const unsigned short*)L + cur*8192 + 4096;

    short8 Kf[4];
    #pragma unroll
    for(int kc=0;kc<4;kc++)
      Kf[kc] = *(const short8*)(Kh + l32*64 + (((2*kc+h) ^ l7)&7)*8);
    #pragma unroll
    for(int qh=0;qh<2;qh++){
      f32x16 S;
      #pragma unroll
      for(int r=0;r<16;r++) S[r] = 0.f;
      #pragma unroll
      for(int kc=0;kc<4;kc++)
        S = __builtin_amdgcn_mfma_f32_32x32x16_bf16(Kf[kc], Qf[qh][kc], S, 0,0,0);
      // reg r at lane (h,l32): kv_local = 16*((r>>3)&1) + 8h + 4*((r>>2)&1) + (r&3) (+32w global)
      f32x16 E;
      if(kvt == qt){                   // diagonal tile (block-uniform branch)
        int dref = 32*qh + l32 - 32*w - 8*h;
        #pragma unroll
        for(int r=0;r<16;r++){
          int kvl = 16*((r>>3)&1) + 4*((r>>2)&1) + (r&3);
          float pv = (kvl == dref) ? 0.f : __builtin_amdgcn_exp2f(S[r]);
          E[r] = pv; lracc[qh][r&3] += pv;
        }
      } else {
        #pragma unroll
        for(int r=0;r<16;r++){
          float pv = __builtin_amdgcn_exp2f(S[r]);
          E[r] = pv; lracc[qh][r&3] += pv;
        }
      }
      // P^T B-frags of this wave's half: chunk c_loc <- regs 8c..8c+7 in order
      pk8 Pb0, Pb1;
      Pb0.u = (u32x4){ pk2t(E[0],E[1]),   pk2t(E[2],E[3]),
                       pk2t(E[4],E[5]),   pk2t(E[6],E[7]) };
      Pb1.u = (u32x4){ pk2t(E[8],E[9]),   pk2t(E[10],E[11]),
                       pk2t(E[12],E[13]), pk2t(E[14],E[15]) };
      // O^T += V^T . P^T over this wave's kv chunks (global chunk = 2w + c_loc)
      #pragma unroll
      for(int hdq=0;hdq<2;hdq++){
        short8 Vf0 = *(const short8*)(Vh + (32*hdq + l32)*64 + (((4*w + h) ^ l7)&7)*8);
        short8 Vf1 = *(const short8*)(Vh + (32*hdq + l32)*64 + (((4*w + 2 + h) ^ l7)&7)*8);
        O[qh][hdq] = __builtin_amdgcn_mfma_f32_32x32x16_bf16(Vf0, Pb0.s, O[qh][hdq], 0,0,0);
        O[qh][hdq] = __builtin_amdgcn_mfma_f32_32x32x16_bf16(Vf1, Pb1.s, O[qh][hdq], 0,0,0);
      }
    }
    __builtin_amdgcn_sched_barrier(0);       // pin: no ds_read sunk below WAR barrier
    asm volatile("" ::: "memory");
    __builtin_amdgcn_s_barrier();            // WAR: buf cur free for overwrite at i+1
    cur ^= 1;
  }
  float lr[2];
  #pragma unroll
  for(int qh=0;qh<2;qh++)
    lr[qh] = (lracc[qh][0] + lracc[qh][1]) + (lracc[qh][2] + lracc[qh][3]);
  // merge the 2 waves' kv-half partials
  lr[0] += __shfl_xor(lr[0],32,64);
  lr[1] += __shfl_xor(lr[1],32,64);
  __syncthreads();                     // L free (all tile reads done)
  if(w == 0){
    #pragma unroll
    for(int qh=0;qh<2;qh++)
      #pragma unroll
      for(int hdq=0;hdq<2;hdq++)
        #pragma unroll
        for(int r=0;r<16;r++)
          L[(qh*32 + hdq*16 + r)*64 + lane] = __float_as_uint(O[qh][hdq][r]);
    Lr[lane]      = lr[0];
    Lr[64 + lane] = lr[1];
  }
  __syncthreads();
  if(w == 1){
    #pragma unroll
    for(int qh=0;qh<2;qh++)
      #pragma unroll
      for(int hdq=0;hdq<2;hdq++)
        #pragma unroll
        for(int r=0;r<16;r++)
          O[qh][hdq][r] += __uint_as_float(L[(qh*32 + hdq*16 + r)*64 + lane]);
    float lt0 = lr[0] + Lr[lane];
    float lt1 = lr[1] + Lr[64 + lane];
    size_t lb = (size_t)sp*TOK_ + (size_t)b*N_ + q0;
    if(lane < 32){ lpart[lb + lane] = lt0; lpart[lb + 32 + lane] = lt1; }
    // transpose O^T -> [q][hd] bf16 in L (in-wave DS ordering: reads above precede writes)
    #pragma unroll
    for(int qh=0;qh<2;qh++){
      int q = 32*qh + l32;
      #pragma unroll
      for(int hdq=0;hdq<2;hdq++)
        #pragma unroll
        for(int k2=0;k2<8;k2++){
          int idx = 16*hdq + 4*(k2>>1) + 2*h + (k2&1);
          L[q*36 + idx] = pk2(O[qh][hdq][2*k2], O[qh][hdq][2*k2+1]);
        }
    }
    unsigned int* og = (unsigned int*)(Opart + ((size_t)sp*TOK_ + (size_t)b*N_ + q0)*64);
    #pragma unroll
    for(int rep=0;rep<8;rep++){
      int f = rep*64 + lane;
      int row = f>>3, c4 = f&7;
      *(u32x4*)(og + row*32 + c4*4) = *(const u32x4*)&L[row*36 + c4*4];
    }
  }
}

// ---------------------------------------------------------------- K3: merge + proj + residual(v) + LN2 + MLP + residual (R9-verified)
__global__ __launch_bounds__(256) void k_mlp(const unsigned short* __restrict__ Opart,
                                             const float* __restrict__ lpart,
                                             const unsigned short* __restrict__ vfb,
                                             const unsigned short* __restrict__ wpj,
                                             const unsigned short* __restrict__ w1b,
                                             const unsigned short* __restrict__ w2b,
                                             const float* __restrict__ projb,
                                             const float* __restrict__ n2w,
                                             const float* __restrict__ n2b,
                                             const float* __restrict__ fc1b,
                                             const float* __restrict__ fc2b,
                                             float* __restrict__ out){
  __shared__ alignas(16) unsigned short Ws[3][64*72];
  __shared__ alignas(16) unsigned short Xs[64*72];
  unsigned int* Xs32 = (unsigned int*)Xs;
  int tid = threadIdx.x;
  int w = tid>>6, lane = tid&63, quad = lane>>4, l16 = lane&15;
  int t0 = blockIdx.x*64;

  {
    #pragma unroll
    for(int rep=0;rep<2;rep++){
      int f = rep*256 + tid;
      int row = f>>3, c = f&7;
      *(u32x4*)((unsigned int*)Ws[0] + row*36 + c*4) = ((const u32x4*)wpj)[row*8+c];
      *(u32x4*)((unsigned int*)Ws[1] + row*36 + c*4) = ((const u32x4*)w1b)[row*8+c];
      *(u32x4*)((unsigned int*)Ws[2] + row*36 + c*4) = ((const u32x4*)w2b)[row*8+c];
    }
  }
  #pragma unroll
  for(int i=0;i<2;i++){
    int f = i*256 + tid;
    int row = f>>3, c = f&7;
    float lo[4] = {0,0,0,0}, hi[4] = {0,0,0,0};
    float lsum = 0.f;
    #pragma unroll
    for(int s=0;s<NSPLIT;s++){
      u32x4 a = *((const u32x4*)(Opart + ((size_t)s*TOK_ + t0)*64) + row*8 + c);
      #pragma unroll
      for(int k=0;k<4;k++){
        lo[k] += __uint_as_float(a[k]<<16);
        hi[k] += __uint_as_float(a[k] & 0xffff0000u);
      }
      lsum += lpart[(size_t)s*TOK_ + t0 + row];
    }
    float linv = 1.f/lsum;
    u32x4 o;
    #pragma unroll
    for(int k=0;k<4;k++) o[k] = pk2(lo[k]*linv, hi[k]*linv);
    *(u32x4*)&Xs32[row*36 + c*4] = o;
  }
  __syncthreads();

  short8 Af[2];
  #pragma unroll
  for(int kk=0;kk<2;kk++)
    Af[kk] = *(const short8*)(Xs + (w*16+l16)*72 + kk*32 + quad*8);
  f32x4 acc[4];
  #pragma unroll
  for(int i=0;i<4;i++) acc[i] = (f32x4){0.f,0.f,0.f,0.f};
  #pragma unroll
  for(int jt=0;jt<4;jt++)
    #pragma unroll
    for(int kk=0;kk<2;kk++){
      short8 Bf = *(const short8*)(Ws[0] + (jt*16+l16)*72 + kk*32 + quad*8);
      acc[jt] = __builtin_amdgcn_mfma_f32_16x16x32_bf16(Af[kk], Bf, acc[jt], 0,0,0);
    }
  float xa[4][4];
  #pragma unroll
  for(int jt=0;jt<4;jt++){
    int col = jt*16 + l16;
    float pb = projb[col];
    #pragma unroll
    for(int r=0;r<4;r++){
      int tg = t0 + w*16 + quad*4 + r;
      xa[jt][r] = acc[jt][r] + pb + b2f(vfb[(size_t)tg*64 + col]);
    }
  }
  #pragma unroll
  for(int r=0;r<4;r++){
    float s = 0.f, sq = 0.f;
    #pragma unroll
    for(int jt=0;jt<4;jt++){ s += xa[jt][r]; sq += xa[jt][r]*xa[jt][r]; }
    s  += __shfl_xor(s,1,64);  s  += __shfl_xor(s,2,64);
    s  += __shfl_xor(s,4,64);  s  += __shfl_xor(s,8,64);
    sq += __shfl_xor(sq,1,64); sq += __shfl_xor(sq,2,64);
    sq += __shfl_xor(sq,4,64); sq += __shfl_xor(sq,8,64);
    float mu = s*(1.f/64.f);
    float var = sq*(1.f/64.f) - mu*mu;
    float rstd = rsqrtf(var + 1e-5f);
    #pragma unroll
    for(int jt=0;jt<4;jt++){
      int col = jt*16 + l16;
      Xs[(w*16+quad*4+r)*72 + col] = f2b((xa[jt][r]-mu)*rstd*n2w[col] + n2b[col]);
    }
  }
  #pragma unroll
  for(int kk=0;kk<2;kk++)
    Af[kk] = *(const short8*)(Xs + (w*16+l16)*72 + kk*32 + quad*8);
  f32x4 acc2[4];
  #pragma unroll
  for(int i=0;i<4;i++) acc2[i] = (f32x4){0.f,0.f,0.f,0.f};
  #pragma unroll
  for(int jt=0;jt<4;jt++)
    #pragma unroll
    for(int kk=0;kk<2;kk++){
      short8 Bf = *(const short8*)(Ws[1] + (jt*16+l16)*72 + kk*32 + quad*8);
      acc2[jt] = __builtin_amdgcn_mfma_f32_16x16x32_bf16(Af[kk], Bf, acc2[jt], 0,0,0);
    }
  #pragma unroll
  for(int jt=0;jt<4;jt++){
    int col = jt*16 + l16;
    float fb = fc1b[col];
    #pragma unroll
    for(int r=0;r<4;r++){
      float g = acc2[jt][r] + fb;
      float z = g*0.70710678118f;
      float az = fabsf(z);
      float t = 1.f/(1.f + 0.3275911f*az);
      float poly = ((((1.061405429f*t - 1.453152027f)*t + 1.421413741f)*t - 0.284496736f)*t + 0.254829592f)*t;
      float er = 1.f - poly*__builtin_amdgcn_exp2f(-az*az*1.44269504089f);
      er = (z < 0.f) ? -er : er;
      Xs[(w*16+quad*4+r)*72 + col] = f2b(0.5f*g*(1.f + er));
    }
  }
  #pragma unroll
  for(int kk=0;kk<2;kk++)
    Af[kk] = *(const short8*)(Xs + (w*16+l16)*72 + kk*32 + quad*8);
  f32x4 acc3[4];
  #pragma unroll
  for(int i=0;i<4;i++) acc3[i] = (f32x4){0.f,0.f,0.f,0.f};
  #pragma unroll
  for(int jt=0;jt<4;jt++)
    #pragma unroll
    for(int kk=0;kk<2;kk++){
      short8 Bf = *(const short8*)(Ws[2] + (jt*16+l16)*72 + kk*32 + quad*8);
      acc3[jt] = __builtin_amdgcn_mfma_f32_16x16x32_bf16(Af[kk], Bf, acc3[jt], 0,0,0);
    }
  #pragma unroll
  for(int jt=0;jt<4;jt++){
    int col = jt*16 + l16;
    float ob2 = fc2b[col];
    #pragma unroll
    for(int r=0;r<4;r++){
      int tg = t0 + w*16 + quad*4 + r;
      out[(size_t)tg*64 + col] = xa[jt][r] + acc3[jt][r] + ob2;
    }
  }
}

// ---------------------------------------------------------------- launch
extern "C" void kernel_launch(void* const* d_in, const int* in_sizes, int n_in,
                              void* d_out, int out_size, void* d_ws, size_t ws_size,
                              hipStream_t stream){
  const float* x     = (const float*)d_in[0];
  const float* n1w   = (const float*)d_in[1];
  const float* n1b   = (const float*)d_in[2];
  const float* qkvw  = (const float*)d_in[3];
  const float* scale = (const float*)d_in[4];
  const float* projw = (const float*)d_in[5];
  const float* projb = (const float*)d_in[6];
  const float* n2w   = (const float*)d_in[7];
  const float* n2b   = (const float*)d_in[8];
  const float* fc1w  = (const float*)d_in[9];
  const float* fc1b  = (const float*)d_in[10];
  const float* fc2w  = (const float*)d_in[11];
  const float* fc2b  = (const float*)d_in[12];

  char* base = (char*)d_ws;
  unsigned short* wp  = (unsigned short*)(base + 0);          //    61440
  unsigned short* wpj = (unsigned short*)(base + 61440);      //     8192
  unsigned short* w1b = (unsigned short*)(base + 69632);      //     8192
  unsigned short* w2b = (unsigned short*)(base + 77824);      //     8192
  unsigned short* qb  = (unsigned short*)(base + 86016);      //  3211264
  unsigned short* kb  = (unsigned short*)(base + 3297280);    //  3211264
  unsigned short* vtb = (unsigned short*)(base + 6508544);    //  3211264
  unsigned short* vfb = (unsigned short*)(base + 9719808);    //  3211264
  unsigned short* Op  = (unsigned short*)(base + 12931072);   // 12845056 (4 splits bf16)
  float*          lp  = (float*)(base + 25776128);            //   401408  -> total 26177536

  hipLaunchKernelGGL(k_prep, dim3(120),        dim3(256), 0, stream,
                     qkvw, projw, fc1w, fc2w, wp, wpj, w1b, w2b);
  hipLaunchKernelGGL(k_qkv,  dim3(TOK_/64),    dim3(256), 0, stream,
                     x, n1w, n1b, wp, scale, qb, kb, vtb, vfb);
  hipLaunchKernelGGL(k_attn, dim3(49,NSPLIT,8), dim3(128), 0, stream, qb, kb, vtb, Op, lp);
  hipLaunchKernelGGL(k_mlp,  dim3(TOK_/64),    dim3(256), 0, stream, Op, lp, vfb,
                     wpj, w1b, w2b, projb, n2w, n2b, fc1b, fc2b, (float*)d_out);
}